// Round 5
// baseline (256.413 us; speedup 1.0000x reference)
//
#include <hip/hip_runtime.h>
#include <hip/hip_bf16.h>

#define N_TOTAL 262144
#define BN_EPS  1e-3f

typedef float f32x4  __attribute__((ext_vector_type(4)));
typedef short bf16x8 __attribute__((ext_vector_type(8)));

typedef __attribute__((address_space(1))) const unsigned int as1cu;
typedef __attribute__((address_space(3))) unsigned int       as3u;

// ws layout:
//   floats [0, 4096)      : gstats replicas — 32 x (sum[64], sumsq[64])
//   bytes  [17408, 91136) : wfrag — 72 B-frags x 64 lanes x 8 bf16
//   bytes  [131072, ...)  : 128B zero row, then featb (N x 64 bf16)
#define WFRAG_OFF 17408
#define FEATB_OFF 131072
#define FEAT_BLOCKS 16384
#define WPACK_BLOCKS 144

// ---------------------------------------------------------------------------
template<bool DO_FEAT>
__global__ void prepare_kernel(const float* __restrict__ feat,
                               unsigned short* __restrict__ featb_region,
                               const float* __restrict__ W,
                               unsigned short* __restrict__ wfrag,
                               float* __restrict__ gstats)
{
    const int b = blockIdx.x;
    if (b < FEAT_BLOCKS) {
        if (DO_FEAT) {
            const size_t i = (size_t)b * 256 + threadIdx.x;   // float4 units
            const float4 v = ((const float4*)feat)[i];
            union { __hip_bfloat162 h[2]; uint2 u; } p;
            p.h[0] = __float22bfloat162_rn(make_float2(v.x, v.y));
            p.h[1] = __float22bfloat162_rn(make_float2(v.z, v.w));
            ((uint2*)(featb_region + 64))[i] = p.u;           // +64: skip zero row
        }
    } else if (b < FEAT_BLOCKS + WPACK_BLOCKS) {
        const int e = (b - FEAT_BLOCKS) * 256 + threadIdx.x;
        const int f  = e >> 9;
        const int r  = e & 511;
        const int L  = r >> 3;
        const int j  = r & 7;
        const int nb = f & 3;
        const int kk = (f >> 2) & 1;
        const int k9 = f >> 3;
        const int kci = kk * 32 + ((L >> 4) << 3) + j;
        const int n   = nb * 16 + (L & 15);
        __hip_bfloat16 bb = __float2bfloat16(W[k9 * 4096 + kci * 64 + n]);
        wfrag[e] = *reinterpret_cast<unsigned short*>(&bb);
    } else {
        for (int i = threadIdx.x; i < 4096; i += 256) gstats[i] = 0.f;
        if (threadIdx.x < 64) featb_region[threadIdx.x] = 0;  // zero row
    }
}

// ---------------------------------------------------------------------------
// Conv via MFMA, async-LDS gather pipeline, A-depth 3 / B-depth 2.
// Block 256 thr = 4 waves, 128 rows/block (tile XCD-swizzled).
// FIFO queue per tap t (verified): issue B(t+2) then A(t+3); wait vmcnt(28)
// drains exactly {A(t), B(t)} — every A has 3 taps of latency cover (L3),
// every B 2 taps (L2). Abuf: 4 bufs x 4 waves x 4KB = 64 KB (IL aliased).
// ---------------------------------------------------------------------------
__global__ __launch_bounds__(256, 2)
void conv_mfma_kernel(const unsigned short* __restrict__ featb,  // after zero row
                      const unsigned short* __restrict__ wfrag,
                      const float* __restrict__ bias,
                      const int*   __restrict__ nb9,
                      float* __restrict__ out,
                      float* __restrict__ gstats)
{
    __shared__ __align__(16) unsigned short Abuf[4 * 4 * 2 * 2 * 512]; // 64 KB
    int* IL = (int*)Abuf;   // aliased: used only before the pipeline starts

    const int tid  = threadIdx.x;
    const int lane = tid & 63;
    const int wave = tid >> 6;
    const int quad = lane >> 4;
    const int l16  = lane & 15;
    const int rowbase = wave * 32;
    // XCD swizzle: each XCD (blk%8) works one contiguous 256-tile range
    const int tile = ((blockIdx.x & 7) << 8) | (blockIdx.x >> 3);

    for (int i = tid; i < 128 * 9; i += 256)
        IL[i] = nb9[(size_t)tile * 1152 + i];
    __syncthreads();

    // per-lane gather offsets (ushort units); invalid -> -64 = zero row
    int ofs[9][2];
#pragma unroll
    for (int t = 0; t < 9; ++t)
#pragma unroll
        for (int mb = 0; mb < 2; ++mb) {
            const int id = IL[(rowbase + mb * 16 + l16) * 9 + t];
            ofs[t][mb] = (id < 0) ? -64 : (id << 6);
        }
    __syncthreads();   // done with IL; Abuf may now be overwritten

    f32x4 acc[2][4];
#pragma unroll
    for (int mb = 0; mb < 2; ++mb)
#pragma unroll
        for (int nb = 0; nb < 4; ++nb)
            acc[mb][nb] = (f32x4){0.f, 0.f, 0.f, 0.f};

    bf16x8 Bf[3][8];

    auto loadBtap = [&](int t) {
#pragma unroll
        for (int f = 0; f < 8; ++f)
            Bf[t % 3][f] = *(const bf16x8*)(wfrag + (t * 8 + f) * 512 + lane * 8);
    };
    auto asyncA = [&](int t) {
        const int buf = t & 3;
#pragma unroll
        for (int mb = 0; mb < 2; ++mb)
#pragma unroll
            for (int kk = 0; kk < 2; ++kk) {
                const unsigned short* g = featb + ofs[t][mb] + kk * 32 + quad * 8;
                unsigned short* l = &Abuf[(((buf * 4 + wave) * 2 + mb) * 2 + kk) * 512];
                __builtin_amdgcn_global_load_lds((as1cu*)g, (as3u*)l, 16, 0, 0);
            }
    };

    // prologue (FIFO order matters): B0, A0, B1, A1, A2  -> 28 outstanding
    loadBtap(0);
    asyncA(0);
    loadBtap(1);
    asyncA(1);
    asyncA(2);

#pragma unroll
    for (int t = 0; t < 9; ++t) {
        if (t + 2 < 9) loadBtap(t + 2);
        if (t + 3 < 9) asyncA(t + 3);
        // drains exactly {A(t), B(t)} (queue sim in header comment)
        if (t < 6)       asm volatile("s_waitcnt vmcnt(28)" ::: "memory");
        else if (t == 6) asm volatile("s_waitcnt vmcnt(24)" ::: "memory");
        else if (t == 7) asm volatile("s_waitcnt vmcnt(12)" ::: "memory");
        else             asm volatile("s_waitcnt vmcnt(0)"  ::: "memory");

        const int buf = t & 3;
#pragma unroll
        for (int kk = 0; kk < 2; ++kk)
#pragma unroll
            for (int mb = 0; mb < 2; ++mb) {
                const bf16x8 a = *(const bf16x8*)
                    &Abuf[(((buf * 4 + wave) * 2 + mb) * 2 + kk) * 512 + lane * 8];
#pragma unroll
                for (int nb = 0; nb < 4; ++nb)
                    acc[mb][nb] = __builtin_amdgcn_mfma_f32_16x16x32_bf16(
                        a, Bf[t % 3][kk * 4 + nb], acc[mb][nb], 0, 0, 0);
            }
    }

    // ---- epilogue: bias, store out, BN partial sums (replica atomics) ----
    const size_t row0 = (size_t)tile * 128 + rowbase;
    const int rep = (tile & 31) * 128;
    float s[4], sq[4];
#pragma unroll
    for (int nb = 0; nb < 4; ++nb) { s[nb] = 0.f; sq[nb] = 0.f; }

#pragma unroll
    for (int nb = 0; nb < 4; ++nb) {
        const float b = bias[nb * 16 + l16];
#pragma unroll
        for (int mb = 0; mb < 2; ++mb) {
            const f32x4 v = acc[mb][nb];
#pragma unroll
            for (int i = 0; i < 4; ++i) {
                const float o = v[i] + b;
                out[(row0 + mb * 16 + quad * 4 + i) * 64 + nb * 16 + l16] = o;
                s[nb]  += o;
                sq[nb] += o * o;
            }
        }
    }
#pragma unroll
    for (int nb = 0; nb < 4; ++nb) {
        float ss = s[nb], qq = sq[nb];
        ss += __shfl_xor(ss, 16, 64);  qq += __shfl_xor(qq, 16, 64);
        ss += __shfl_xor(ss, 32, 64);  qq += __shfl_xor(qq, 32, 64);
        if (quad == 0) {
            atomicAdd(&gstats[rep + nb * 16 + l16],      ss);
            atomicAdd(&gstats[rep + 64 + nb * 16 + l16], qq);
        }
    }
}

// ---------------------------------------------------------------------------
// Fallback (tiny ws): correct but slow fp32 path. Not expected to run.
// ---------------------------------------------------------------------------
__global__ void conv_fallback_kernel(const float* __restrict__ feat,
                                     const float* __restrict__ W,
                                     const float* __restrict__ bias,
                                     const int* __restrict__ nb9,
                                     float* __restrict__ out,
                                     float* __restrict__ gstats)
{
    const int n = blockIdx.x;
    const int c = threadIdx.x;   // 64 threads
    float a = bias[c];
    for (int k = 0; k < 9; ++k) {
        const int id = nb9[(size_t)n * 9 + k];
        if (id >= 0) {
            const float* fr = feat + (size_t)id * 64;
            const float* wk = W + k * 4096 + c;
            for (int ci = 0; ci < 64; ++ci) a = fmaf(fr[ci], wk[ci * 64], a);
        }
    }
    out[(size_t)n * 64 + c] = a;
    atomicAdd(&gstats[(n & 31) * 128 + c], a);
    atomicAdd(&gstats[(n & 31) * 128 + 64 + c], a * a);
}

__global__ void zero_stats_kernel(float* __restrict__ gstats)
{
    for (int i = threadIdx.x + blockIdx.x * 256; i < 4096; i += 256 * 16)
        gstats[i] = 0.f;
}

// ---------------------------------------------------------------------------
// Fused BN stats + apply: each block reduces the 32 replicas to scale/shift
// (LDS), then grid-strides 4 float4 chunks of out -> out_bn.
// ---------------------------------------------------------------------------
__global__ void bn_apply_kernel(const float* __restrict__ out,
                                const float* __restrict__ gs,
                                const float* __restrict__ gamma,
                                const float* __restrict__ beta,
                                float* __restrict__ out_bn)
{
    __shared__ float sc_s[64], sh_s[64];
    const int t = threadIdx.x;
    if (t < 64) {
        float s = 0.f, q = 0.f;
#pragma unroll
        for (int r = 0; r < 32; ++r) { s += gs[r * 128 + t]; q += gs[r * 128 + 64 + t]; }
        const float inv_n = 1.f / (float)N_TOTAL;
        const float mean  = s * inv_n;
        const float var   = q * inv_n - mean * mean;
        const float sc    = gamma[t] * rsqrtf(var + BN_EPS);
        sc_s[t] = sc;
        sh_s[t] = beta[t] - mean * sc;
    }
    __syncthreads();
#pragma unroll
    for (int it = 0; it < 4; ++it) {
        const size_t i  = ((size_t)blockIdx.x * 4 + it) * 256 + t;  // float4 idx
        const int    c4 = ((int)i & 15) << 2;
        const float4 v  = ((const float4*)out)[i];
        float4 o;
        o.x = fmaf(v.x, sc_s[c4],     sh_s[c4]);
        o.y = fmaf(v.y, sc_s[c4 + 1], sh_s[c4 + 1]);
        o.z = fmaf(v.z, sc_s[c4 + 2], sh_s[c4 + 2]);
        o.w = fmaf(v.w, sc_s[c4 + 3], sh_s[c4 + 3]);
        ((float4*)out_bn)[i] = o;
    }
}

extern "C" void kernel_launch(void* const* d_in, const int* in_sizes, int n_in,
                              void* d_out, int out_size, void* d_ws, size_t ws_size,
                              hipStream_t stream)
{
    const float* feat  = (const float*)d_in[0];   // (N, 64)
    const float* W     = (const float*)d_in[1];   // (9, 64, 64)
    const float* bias  = (const float*)d_in[2];
    const float* gamma = (const float*)d_in[3];
    const float* beta  = (const float*)d_in[4];
    const int*   nb9   = (const int*)  d_in[5];   // (N, 9)

    float* out    = (float*)d_out;
    float* out_bn = out + (size_t)N_TOTAL * 64;

    float*          gstats       = (float*)d_ws;
    unsigned short* wfrag        = (unsigned short*)((char*)d_ws + WFRAG_OFF);
    unsigned short* featb_region = (unsigned short*)((char*)d_ws + FEATB_OFF);

    const bool use_featb =
        ws_size >= (size_t)FEATB_OFF + 128 + (size_t)N_TOTAL * 64 * sizeof(unsigned short);

    if (use_featb) {
        prepare_kernel<true><<<FEAT_BLOCKS + WPACK_BLOCKS + 1, 256, 0, stream>>>(
            feat, featb_region, W, wfrag, gstats);
        conv_mfma_kernel<<<N_TOTAL / 128, 256, 0, stream>>>(
            featb_region + 64, wfrag, bias, nb9, out, gstats);
    } else {
        zero_stats_kernel<<<16, 256, 0, stream>>>(gstats);
        conv_fallback_kernel<<<N_TOTAL, 64, 0, stream>>>(
            feat, W, bias, nb9, out, gstats);
    }
    bn_apply_kernel<<<(N_TOTAL * 64 / 4) / (256 * 4), 256, 0, stream>>>(
        out, gstats, gamma, beta, out_bn);
}